// Round 1
// baseline (247.327 us; speedup 1.0000x reference)
//
#include <hip/hip_runtime.h>
#include <stdint.h>

// Problem constants (fixed by setup_inputs)
#define TOKENS 64
#define IN_F   4096
#define OUT_F  11008
#define RANK   16
#define GS     128
#define NG     32            // IN_F / GS
#define QROWS  (IN_F / 8)    // 512 packed rows
#define ZCOLS  (OUT_F / 8)   // 1376 packed zero cols
#define LORA_SCALE 2.0f      // lora_alpha / r = 32/16

// ---------------------------------------------------------------------------
// Kernel A: mid[t][j] = sum_k x[t][k] * lora_A[j][k]   (64x16 dots of 4096)
// one wave per (t,j) pair; 1024 waves = 256 blocks x 256 threads
// ---------------------------------------------------------------------------
__global__ __launch_bounds__(256) void lora_mid_kernel(
        const float* __restrict__ x,
        const float* __restrict__ loraA,
        float* __restrict__ mid) {
    const int wave = (blockIdx.x * 256 + threadIdx.x) >> 6;  // [0,1024)
    const int lane = threadIdx.x & 63;
    const int t = wave >> 4;
    const int j = wave & 15;
    const float* xr = x + t * IN_F;
    const float* ar = loraA + j * IN_F;
    float s = 0.f;
    for (int k = lane; k < IN_F; k += 64) s += xr[k] * ar[k];
    #pragma unroll
    for (int off = 32; off; off >>= 1) s += __shfl_down(s, off);
    if (lane == 0) mid[t * RANK + j] = s;
}

// ---------------------------------------------------------------------------
// Kernel B: out[t][o] = LORA_SCALE * sum_j mid[t][j] * lora_B[o][j]
// plain store — initializes d_out (poisoned by harness) before kernel C's atomics
// ---------------------------------------------------------------------------
__global__ __launch_bounds__(256) void lora_out_kernel(
        const float* __restrict__ mid,
        const float* __restrict__ loraB,
        float* __restrict__ out) {
    const int gid = blockIdx.x * 256 + threadIdx.x;  // [0, 704512)
    const int t = gid / OUT_F;
    const int o = gid - t * OUT_F;
    const float4* b4 = (const float4*)(loraB + o * RANK);
    const float4* m4 = (const float4*)(mid + t * RANK);
    float s = 0.f;
    #pragma unroll
    for (int i = 0; i < 4; ++i) {
        float4 b = b4[i];
        float4 m = m4[i];
        s += b.x * m.x + b.y * m.y + b.z * m.z + b.w * m.w;
    }
    out[gid] = s * LORA_SCALE;
}

// ---------------------------------------------------------------------------
// Kernel C: out[t][o] += sum_k x[t][k] * scale[g][o]*(nib(qw,k,o) - (nib(qz,g,o)+1))
// block = 256 threads: (tid&127) -> column pair, (tid>>7) -> token half.
// Each thread: 2 adjacent columns x 32 tokens (64 fp32 acc).
// Grid: (OUT_F/256, 16) — blockIdx.y = split-K over pairs of 128-groups.
// x chunk (64 tokens x 128 k = 32 KB) staged in LDS; reads are wave-broadcast.
// ---------------------------------------------------------------------------
__global__ __launch_bounds__(256) void main_gemm_kernel(
        const float* __restrict__ x,
        const uint32_t* __restrict__ qw,
        const uint32_t* __restrict__ qz,
        const float* __restrict__ scales,
        float* __restrict__ out) {
    __shared__ float xs[TOKENS * GS];  // 32 KB

    const int tid = threadIdx.x;
    const int o   = blockIdx.x * 256 + (tid & 127) * 2;  // even column
    const int th  = tid >> 7;                            // token half: 0 or 1
    const int g0  = blockIdx.y * 2;                      // two groups per block

    float acc0[32], acc1[32];
    #pragma unroll
    for (int t = 0; t < 32; ++t) { acc0[t] = 0.f; acc1[t] = 0.f; }

    for (int gg = 0; gg < 2; ++gg) {
        const int g   = g0 + gg;
        const int kc0 = g * GS;

        __syncthreads();  // protect xs from previous iteration's readers
        #pragma unroll
        for (int i = 0; i < 32; ++i) {
            int idx = tid + i * 256;          // [0, 8192)
            int t  = idx >> 7;
            int kk = idx & 127;
            xs[idx] = x[t * IN_F + kc0 + kk]; // coalesced, conflict-free
        }
        __syncthreads();

        // per-group dequant constants for the 2 columns
        const float2 s2 = *(const float2*)(scales + g * OUT_F + o);
        const uint32_t zq = qz[g * ZCOLS + (o >> 3)];
        const float z0 = (float)(((zq >> ((o & 7) * 4)) & 0xFu) + 1u);
        const float z1 = (float)(((zq >> (((o & 7) + 1) * 4)) & 0xFu) + 1u);
        const float sz0 = s2.x * z0;
        const float sz1 = s2.y * z1;

        for (int k8 = 0; k8 < 16; ++k8) {  // 16 packed rows per group
            const uint2 q2 = *(const uint2*)(qw + (size_t)(g * 16 + k8) * OUT_F + o);
            float w0[8], w1[8];
            #pragma unroll
            for (int j = 0; j < 8; ++j) {
                w0[j] = fmaf((float)((q2.x >> (4 * j)) & 0xFu), s2.x, -sz0);
                w1[j] = fmaf((float)((q2.y >> (4 * j)) & 0xFu), s2.y, -sz1);
            }
            // token base for this half
            const float4* xr = (const float4*)&xs[th * 32 * GS + k8 * 8];
            #pragma unroll
            for (int tt = 0; tt < 32; ++tt) {
                float4 a0 = xr[tt * 32];      // xs[(th*32+tt)*128 + k8*8 .. +3]
                float4 a1 = xr[tt * 32 + 1];  // .. +4 .. +7
                acc0[tt] = fmaf(a0.x, w0[0], acc0[tt]);
                acc1[tt] = fmaf(a0.x, w1[0], acc1[tt]);
                acc0[tt] = fmaf(a0.y, w0[1], acc0[tt]);
                acc1[tt] = fmaf(a0.y, w1[1], acc1[tt]);
                acc0[tt] = fmaf(a0.z, w0[2], acc0[tt]);
                acc1[tt] = fmaf(a0.z, w1[2], acc1[tt]);
                acc0[tt] = fmaf(a0.w, w0[3], acc0[tt]);
                acc1[tt] = fmaf(a0.w, w1[3], acc1[tt]);
                acc0[tt] = fmaf(a1.x, w0[4], acc0[tt]);
                acc1[tt] = fmaf(a1.x, w1[4], acc1[tt]);
                acc0[tt] = fmaf(a1.y, w0[5], acc0[tt]);
                acc1[tt] = fmaf(a1.y, w1[5], acc1[tt]);
                acc0[tt] = fmaf(a1.z, w0[6], acc0[tt]);
                acc1[tt] = fmaf(a1.z, w1[6], acc1[tt]);
                acc0[tt] = fmaf(a1.w, w0[7], acc0[tt]);
                acc1[tt] = fmaf(a1.w, w1[7], acc1[tt]);
            }
        }
    }

    // split-K combine: 16 partials per output element
    #pragma unroll
    for (int tt = 0; tt < 32; ++tt) {
        const int t = th * 32 + tt;
        atomicAdd(&out[t * OUT_F + o],     acc0[tt]);
        atomicAdd(&out[t * OUT_F + o + 1], acc1[tt]);
    }
}

// ---------------------------------------------------------------------------
extern "C" void kernel_launch(void* const* d_in, const int* in_sizes, int n_in,
                              void* d_out, int out_size, void* d_ws, size_t ws_size,
                              hipStream_t stream) {
    const float*    x      = (const float*)d_in[0];
    const uint32_t* qw     = (const uint32_t*)d_in[1];
    const uint32_t* qz     = (const uint32_t*)d_in[2];
    const float*    scales = (const float*)d_in[3];
    const float*    loraA  = (const float*)d_in[4];
    const float*    loraB  = (const float*)d_in[5];
    float* out = (float*)d_out;
    float* mid = (float*)d_ws;  // 64*16 floats = 4 KB scratch

    lora_mid_kernel<<<256, 256, 0, stream>>>(x, loraA, mid);
    lora_out_kernel<<<(TOKENS * OUT_F) / 256, 256, 0, stream>>>(mid, loraB, out);
    main_gemm_kernel<<<dim3(OUT_F / 256, 16), 256, 0, stream>>>(x, qw, qz, scales, out);
}

// Round 2
// 145.989 us; speedup vs baseline: 1.6941x; 1.6941x over previous
//
#include <hip/hip_runtime.h>
#include <stdint.h>

// Problem constants (fixed by setup_inputs)
#define TOKENS 64
#define IN_F   4096
#define OUT_F  11008
#define RANK   16
#define GS     128
#define NG     32            // IN_F / GS
#define ZCOLS  (OUT_F / 8)   // 1376 packed zero cols
#define LORA_SCALE 2.0f      // lora_alpha / r = 32/16

using short8  = __attribute__((ext_vector_type(8))) short;
using float4v = __attribute__((ext_vector_type(4))) float;

// round-to-nearest-even fp32 -> bf16 bits; also returns the rounded-back fp32
static __device__ inline uint16_t f2bf(float f, float* back) {
    uint32_t u = __float_as_uint(f);
    uint32_t r = (u + 0x7FFFu + ((u >> 16) & 1u)) >> 16;
    *back = __uint_as_float(r << 16);
    return (uint16_t)r;
}

// ---------------------------------------------------------------------------
// P0: x fp32 -> xb bf16 [64][4096], and xsum[t][g] = sum over group of bf16(x)
// block per token; thread tid owns 16 consecutive k (all within group tid/8)
// ---------------------------------------------------------------------------
__global__ __launch_bounds__(256) void prep_kernel(
        const float* __restrict__ x,
        uint16_t* __restrict__ xb,
        float* __restrict__ xsum) {
    __shared__ float red[256];
    const int t   = blockIdx.x;
    const int tid = threadIdx.x;
    const float4* xp = (const float4*)(x + (size_t)t * IN_F + tid * 16);
    union { uint16_t u[16]; uint4 q[2]; } ob;
    float s = 0.f;
    #pragma unroll
    for (int i = 0; i < 4; ++i) {
        float4 v = xp[i];
        float b;
        ob.u[i*4+0] = f2bf(v.x, &b); s += b;
        ob.u[i*4+1] = f2bf(v.y, &b); s += b;
        ob.u[i*4+2] = f2bf(v.z, &b); s += b;
        ob.u[i*4+3] = f2bf(v.w, &b); s += b;
    }
    uint4* op = (uint4*)(xb + (size_t)t * IN_F + tid * 16);
    op[0] = ob.q[0];
    op[1] = ob.q[1];
    red[tid] = s;
    __syncthreads();
    if (tid < NG) {  // 32 groups, 8 threads each
        float g = 0.f;
        #pragma unroll
        for (int j = 0; j < 8; ++j) g += red[tid * 8 + j];
        xsum[t * NG + tid] = g;
    }
}

// ---------------------------------------------------------------------------
// Kernel A: mid[t][j] = sum_k x[t][k] * lora_A[j][k]
// ---------------------------------------------------------------------------
__global__ __launch_bounds__(256) void lora_mid_kernel(
        const float* __restrict__ x,
        const float* __restrict__ loraA,
        float* __restrict__ mid) {
    const int wave = (blockIdx.x * 256 + threadIdx.x) >> 6;  // [0,1024)
    const int lane = threadIdx.x & 63;
    const int t = wave >> 4;
    const int j = wave & 15;
    const float* xr = x + t * IN_F;
    const float* ar = loraA + j * IN_F;
    float s = 0.f;
    for (int k = lane; k < IN_F; k += 64) s += xr[k] * ar[k];
    #pragma unroll
    for (int off = 32; off; off >>= 1) s += __shfl_down(s, off);
    if (lane == 0) mid[t * RANK + j] = s;
}

// ---------------------------------------------------------------------------
// Kernel B: out[t][o] = LORA_SCALE * sum_j mid[t][j] * lora_B[o][j]
// plain store — initializes d_out before main kernel's atomics
// ---------------------------------------------------------------------------
__global__ __launch_bounds__(256) void lora_out_kernel(
        const float* __restrict__ mid,
        const float* __restrict__ loraB,
        float* __restrict__ out) {
    const int gid = blockIdx.x * 256 + threadIdx.x;
    const int t = gid / OUT_F;
    const int o = gid - t * OUT_F;
    const float4* b4 = (const float4*)(loraB + o * RANK);
    const float4* m4 = (const float4*)(mid + t * RANK);
    float s = 0.f;
    #pragma unroll
    for (int i = 0; i < 4; ++i) {
        float4 b = b4[i];
        float4 m = m4[i];
        s += b.x * m.x + b.y * m.y + b.z * m.z + b.w * m.w;
    }
    out[gid] = s * LORA_SCALE;
}

// ---------------------------------------------------------------------------
// Main MFMA kernel.
// Block 256 = 4 waves; wave w covers 16 cols (n0 = bx*64 + w*16), all 64 tokens
// (4 M-tiles of 16), K-chunk = 512 (4 groups), split-K via blockIdx.y (8).
// B fragment: lane (n=lane&15, quad=lane>>4) loads qw[(k0/8+quad)][n0+n] — one
// int32 = 8 nibbles = the 8-element bf16 fragment via the 0x4300 trick
// (feeds 128+q; the 128 and GPTQ zero are removed per group via xsum).
// A staged in LDS (row stride 136 bf16 to spread banks).
// ---------------------------------------------------------------------------
__global__ __launch_bounds__(256) void main_gemm_kernel(
        const uint32_t* __restrict__ qw,
        const uint32_t* __restrict__ qz,
        const float* __restrict__ scales,
        const uint16_t* __restrict__ xb,
        const float* __restrict__ xsum,
        float* __restrict__ out) {
    __shared__ uint16_t xs[64 * 136];   // 17408 B
    __shared__ float xsl[4][64];        // xsum slice for this block's 4 groups

    const int tid  = threadIdx.x;
    const int wv   = tid >> 6;
    const int lane = tid & 63;
    const int n    = lane & 15;
    const int quad = lane >> 4;
    const int col  = blockIdx.x * 64 + wv * 16 + n;
    const int g0   = blockIdx.y * 4;
    const int c16  = tid & 15;

    // stage xsum slice (visible after first barrier)
    xsl[tid >> 6][tid & 63] = xsum[(tid & 63) * NG + g0 + (tid >> 6)];

    float4v accf[4];
    #pragma unroll
    for (int mt = 0; mt < 4; ++mt)
        accf[mt] = (float4v){0.f, 0.f, 0.f, 0.f};

    #pragma unroll 1
    for (int gl = 0; gl < 4; ++gl) {
        const int g     = g0 + gl;
        const int kbase = g * GS;

        // B loads for this group's 4 K-steps (independent of LDS — in flight
        // across the staging barriers)
        uint32_t bq[4];
        const uint32_t* qwp = qw + (size_t)(g * 16 + quad) * OUT_F + col;
        #pragma unroll
        for (int ks = 0; ks < 4; ++ks)
            bq[ks] = qwp[(size_t)(ks * 4) * OUT_F];

        // stage A chunk: 64 tokens x 128 k bf16
        uint4 u[4];
        #pragma unroll
        for (int i = 0; i < 4; ++i) {
            int trow = (i * 256 + tid) >> 4;
            u[i] = *(const uint4*)(xb + (size_t)trow * IN_F + kbase + c16 * 8);
        }
        __syncthreads();   // previous group's readers done
        #pragma unroll
        for (int i = 0; i < 4; ++i) {
            int trow = (i * 256 + tid) >> 4;
            *(uint4*)(xs + trow * 136 + c16 * 8) = u[i];
        }
        __syncthreads();

        float4v accg[4];
        #pragma unroll
        for (int mt = 0; mt < 4; ++mt)
            accg[mt] = (float4v){0.f, 0.f, 0.f, 0.f};

        #pragma unroll
        for (int ks = 0; ks < 4; ++ks) {
            // dequant: int32 -> 8 bf16 of (128 + q)
            uint32_t q  = bq[ks];
            uint32_t lo = q & 0x0F0F0F0Fu;
            uint32_t hi = (q >> 4) & 0x0F0F0F0Fu;
            union { uint32_t u32[4]; short8 s8; } bf;
            #pragma unroll
            for (int i = 0; i < 4; ++i)
                bf.u32[i] = __builtin_amdgcn_perm(hi, lo, 0x0C040C00u + i * 0x00010001u)
                            | 0x43004300u;
            #pragma unroll
            for (int mt = 0; mt < 4; ++mt) {
                const uint16_t* ap = xs + (mt * 16 + n) * 136 + ks * 32 + quad * 8;
                short8 af = *(const short8*)ap;
                accg[mt] = __builtin_amdgcn_mfma_f32_16x16x32_bf16(af, bf.s8, accg[mt], 0, 0, 0);
            }
        }

        // fold group: accf += s * (accg - (z + 1 + 128) * xsum)
        const float scl = scales[(size_t)g * OUT_F + col];
        const uint32_t zq = qz[(size_t)g * ZCOLS + (col >> 3)];
        const float zoff = (float)(((zq >> ((col & 7) * 4)) & 0xFu) + 129u);
        #pragma unroll
        for (int mt = 0; mt < 4; ++mt) {
            const float4v xv = *(const float4v*)&xsl[gl][mt * 16 + quad * 4];
            #pragma unroll
            for (int r = 0; r < 4; ++r)
                accf[mt][r] = fmaf(scl, fmaf(-zoff, xv[r], accg[mt][r]), accf[mt][r]);
        }
    }

    // split-K combine
    #pragma unroll
    for (int mt = 0; mt < 4; ++mt) {
        #pragma unroll
        for (int r = 0; r < 4; ++r) {
            int t = mt * 16 + quad * 4 + r;
            atomicAdd(out + (size_t)t * OUT_F + col, accf[mt][r]);
        }
    }
}

// ---------------------------------------------------------------------------
extern "C" void kernel_launch(void* const* d_in, const int* in_sizes, int n_in,
                              void* d_out, int out_size, void* d_ws, size_t ws_size,
                              hipStream_t stream) {
    const float*    x      = (const float*)d_in[0];
    const uint32_t* qw     = (const uint32_t*)d_in[1];
    const uint32_t* qz     = (const uint32_t*)d_in[2];
    const float*    scales = (const float*)d_in[3];
    const float*    loraA  = (const float*)d_in[4];
    const float*    loraB  = (const float*)d_in[5];
    float* out = (float*)d_out;

    // ws layout: xb bf16 [64][4096] (512 KB) | xsum [64][32] | mid [64][16]
    uint16_t* xb   = (uint16_t*)d_ws;
    float*    xsum = (float*)((char*)d_ws + (size_t)TOKENS * IN_F * 2);
    float*    mid  = xsum + TOKENS * NG;

    prep_kernel<<<TOKENS, 256, 0, stream>>>(x, xb, xsum);
    lora_mid_kernel<<<256, 256, 0, stream>>>(x, loraA, mid);
    lora_out_kernel<<<(TOKENS * OUT_F) / 256, 256, 0, stream>>>(mid, loraB, out);
    main_gemm_kernel<<<dim3(OUT_F / 64, 8), 256, 0, stream>>>(qw, qz, scales, xb, xsum, out);
}